// Round 2
// baseline (118.567 us; speedup 1.0000x reference)
//
#include <hip/hip_runtime.h>

#define HH 4096
#define WW 4096
// W4q = WW/4 = 1024 float4-quarters per row

__device__ __forceinline__ float fast_tanh(float x) {
    // tanh(x) = 1 - 2/(exp(2x)+1); saturates to +-1 correctly for |x| large.
    float e = __expf(2.0f * x);
    return 1.0f - 2.0f * __builtin_amdgcn_rcpf(e + 1.0f);
}

__global__ __launch_bounds__(256) void bio_kernel(
    const float* __restrict__ v,
    const float* __restrict__ na,
    const float* __restrict__ kk,
    const float* __restrict__ ca,
    float* __restrict__ out)
{
    // XCD-aware swizzle: hardware round-robins physical block ids across the
    // 8 XCDs; remap so each XCD owns a contiguous band of rows -> vertical
    // stencil reuse hits that XCD's own L2. gridDim.x = 8192 (div by 8).
    int bid   = blockIdx.x;
    int chunk = gridDim.x >> 3;
    int lb    = (bid & 7) * chunk + (bid >> 3);
    int tid   = lb * 256 + (int)threadIdx.x;

    int rp = tid >> 10;        // row-pair index, 0..2047
    int c4 = tid & 1023;       // float4 column quarter
    int c  = c4 * 4;
    int r0 = rp << 1;
    int r1 = r0 + 1;

    int b0 = r0 * WW + c;
    int b1 = b0 + WW;
    int rup = (r0 == 0)      ? 1      : r0 - 1;   // reflect (exclude edge)
    int rdn = (r1 == HH - 1) ? HH - 2 : r1 + 1;

    float4 vu = *(const float4*)(v + rup * WW + c);
    float4 v0 = *(const float4*)(v + b0);
    float4 v1 = *(const float4*)(v + b1);
    float4 vd = *(const float4*)(v + rdn * WW + c);

    float l0, l1, re0, re1;
    if (c == 0) { l0 = v[b0 + 1]; l1 = v[b1 + 1]; }       // reflect left
    else        { l0 = v[b0 - 1]; l1 = v[b1 - 1]; }
    if (c + 4 == WW) { re0 = v[b0 + 2]; re1 = v[b1 + 2]; } // reflect right (col WW-2)
    else             { re0 = v[b0 + 4]; re1 = v[b1 + 4]; }

    float4 na0 = *(const float4*)(na + b0);
    float4 na1 = *(const float4*)(na + b1);
    float4 k0  = *(const float4*)(kk + b0);
    float4 k1  = *(const float4*)(kk + b1);
    float4 ca0 = *(const float4*)(ca + b0);
    float4 ca1 = *(const float4*)(ca + b1);

    float cv[2][4] = {{v0.x, v0.y, v0.z, v0.w}, {v1.x, v1.y, v1.z, v1.w}};
    float up[2][4] = {{vu.x, vu.y, vu.z, vu.w}, {v0.x, v0.y, v0.z, v0.w}};
    float dn[2][4] = {{v1.x, v1.y, v1.z, v1.w}, {vd.x, vd.y, vd.z, vd.w}};
    float lf[2][4] = {{l0, v0.x, v0.y, v0.z}, {l1, v1.x, v1.y, v1.z}};
    float rt[2][4] = {{v0.y, v0.z, v0.w, re0}, {v1.y, v1.z, v1.w, re1}};
    float nai[2][4] = {{na0.x, na0.y, na0.z, na0.w}, {na1.x, na1.y, na1.z, na1.w}};
    float ki[2][4]  = {{k0.x, k0.y, k0.z, k0.w},     {k1.x, k1.y, k1.z, k1.w}};
    float cai[2][4] = {{ca0.x, ca0.y, ca0.z, ca0.w}, {ca1.x, ca1.y, ca1.z, ca1.w}};

    const int HW = HH * WW;
    float ov[2][4], ona[2][4], okk[2][4], oca[2][4];
#pragma unroll
    for (int i = 0; i < 2; ++i) {
#pragma unroll
        for (int j = 0; j < 4; ++j) {
            float lap  = up[i][j] + dn[i][j] + lf[i][j] + rt[i][j] - 4.0f * cv[i][j];
            float vupd = 0.5f * lap + 0.1f * nai[i][j] - 0.05f * ki[i][j] + 0.08f * cai[i][j];
            float nv   = fast_tanh(cv[i][j] + 0.1f * vupd);
            ov[i][j]  = nv;
            ona[i][j] = nai[i][j] * 0.95f + 0.05f * fmaxf(nv, 0.0f);
            okk[i][j] = ki[i][j]  * 0.95f + 0.05f * fmaxf(-nv, 0.0f);
            oca[i][j] = cai[i][j] * 0.95f + 0.05f * fabsf(nv);
        }
    }

#pragma unroll
    for (int i = 0; i < 2; ++i) {
        int b = (i == 0) ? b0 : b1;
        *(float4*)(out + b)          = make_float4(ov[i][0],  ov[i][1],  ov[i][2],  ov[i][3]);
        *(float4*)(out + HW + b)     = make_float4(ona[i][0], ona[i][1], ona[i][2], ona[i][3]);
        *(float4*)(out + 2 * HW + b) = make_float4(okk[i][0], okk[i][1], okk[i][2], okk[i][3]);
        *(float4*)(out + 3 * HW + b) = make_float4(oca[i][0], oca[i][1], oca[i][2], oca[i][3]);
    }
}

extern "C" void kernel_launch(void* const* d_in, const int* in_sizes, int n_in,
                              void* d_out, int out_size, void* d_ws, size_t ws_size,
                              hipStream_t stream) {
    const float* v  = (const float*)d_in[0];
    const float* na = (const float*)d_in[1];
    const float* kk = (const float*)d_in[2];
    const float* ca = (const float*)d_in[3];
    float* out = (float*)d_out;

    int total = (HH / 2) * (WW / 4);     // 2M threads, 2 rows x 4 cols each
    int block = 256;
    int grid  = total / block;           // 8192, divisible by 8 (XCD swizzle)
    bio_kernel<<<grid, block, 0, stream>>>(v, na, kk, ca, out);
}

// Round 3
// 100.786 us; speedup vs baseline: 1.1764x; 1.1764x over previous
//
#include <hip/hip_runtime.h>

#define HH 4096
#define WW 4096

typedef float v4f __attribute__((ext_vector_type(4)));

__device__ __forceinline__ float fast_tanh(float x) {
    // tanh(x) = 1 - 2/(exp(2x)+1); saturates correctly for |x| large.
    float e = __expf(2.0f * x);
    return 1.0f - 2.0f * __builtin_amdgcn_rcpf(e + 1.0f);
}

__global__ __launch_bounds__(256) void bio_kernel(
    const float* __restrict__ v,
    const float* __restrict__ na,
    const float* __restrict__ kk,
    const float* __restrict__ ca,
    float* __restrict__ out)
{
    int tid = blockIdx.x * 256 + (int)threadIdx.x;   // 4M threads
    int r  = tid >> 10;        // row, 0..4095  (1024 float4-quarters/row)
    int c4 = tid & 1023;
    int c  = c4 * 4;
    int base = r * WW + c;

    // reflect padding (mirror excluding edge)
    int rup = (r == 0)      ? 1      : r - 1;
    int rdn = (r == HH - 1) ? HH - 2 : r + 1;

    // voltage: cached loads (stencil halo is the only reused data)
    v4f vc = *(const v4f*)(v + base);
    v4f vu = *(const v4f*)(v + rup * WW + c);
    v4f vd = *(const v4f*)(v + rdn * WW + c);
    float vl = (c == 0)      ? v[base + 1] : v[base - 1];
    float vr = (c + 4 == WW) ? v[base + 2] : v[base + 4];

    // single-use streams: non-temporal loads, keep L2/L3 for voltage
    v4f na4 = __builtin_nontemporal_load((const v4f*)(na + base));
    v4f k4  = __builtin_nontemporal_load((const v4f*)(kk + base));
    v4f ca4 = __builtin_nontemporal_load((const v4f*)(ca + base));

    float cv[4]  = {vc.x, vc.y, vc.z, vc.w};
    float uu[4]  = {vu.x, vu.y, vu.z, vu.w};
    float dd[4]  = {vd.x, vd.y, vd.z, vd.w};
    float lf[4]  = {vl,   vc.x, vc.y, vc.z};
    float rt[4]  = {vc.y, vc.z, vc.w, vr};
    float nai[4] = {na4.x, na4.y, na4.z, na4.w};
    float ki[4]  = {k4.x,  k4.y,  k4.z,  k4.w};
    float cai[4] = {ca4.x, ca4.y, ca4.z, ca4.w};

    v4f ov, ona, okk, oca;
    float o0[4], o1[4], o2[4], o3[4];
#pragma unroll
    for (int i = 0; i < 4; ++i) {
        float lap  = uu[i] + dd[i] + lf[i] + rt[i] - 4.0f * cv[i];
        float vupd = 0.5f * lap + 0.1f * nai[i] - 0.05f * ki[i] + 0.08f * cai[i];
        float nv   = fast_tanh(cv[i] + 0.1f * vupd);
        o0[i] = nv;
        o1[i] = nai[i] * 0.95f + 0.05f * fmaxf(nv, 0.0f);
        o2[i] = ki[i]  * 0.95f + 0.05f * fmaxf(-nv, 0.0f);
        o3[i] = cai[i] * 0.95f + 0.05f * fabsf(nv);
    }
    ov  = (v4f){o0[0], o0[1], o0[2], o0[3]};
    ona = (v4f){o1[0], o1[1], o1[2], o1[3]};
    okk = (v4f){o2[0], o2[1], o2[2], o2[3]};
    oca = (v4f){o3[0], o3[1], o3[2], o3[3]};

    const int HW = HH * WW;
    // streaming outputs: non-temporal, don't pollute L2/L3
    __builtin_nontemporal_store(ov,  (v4f*)(out + base));
    __builtin_nontemporal_store(ona, (v4f*)(out + HW + base));
    __builtin_nontemporal_store(okk, (v4f*)(out + 2 * HW + base));
    __builtin_nontemporal_store(oca, (v4f*)(out + 3 * HW + base));
}

extern "C" void kernel_launch(void* const* d_in, const int* in_sizes, int n_in,
                              void* d_out, int out_size, void* d_ws, size_t ws_size,
                              hipStream_t stream) {
    const float* v  = (const float*)d_in[0];
    const float* na = (const float*)d_in[1];
    const float* kk = (const float*)d_in[2];
    const float* ca = (const float*)d_in[3];
    float* out = (float*)d_out;

    int total = HH * (WW / 4);           // 4M threads, 4 cols each
    int block = 256;
    int grid  = (total + block - 1) / block;   // 16384
    bio_kernel<<<grid, block, 0, stream>>>(v, na, kk, ca, out);
}

// Round 4
// 94.948 us; speedup vs baseline: 1.2488x; 1.0615x over previous
//
#include <hip/hip_runtime.h>

#define HH 4096
#define WW 4096

typedef float v4f __attribute__((ext_vector_type(4)));

__device__ __forceinline__ float fast_tanh(float x) {
    // tanh(x) = 1 - 2/(exp(2x)+1); saturates correctly for |x| large.
    float e = __expf(2.0f * x);
    return 1.0f - 2.0f * __builtin_amdgcn_rcpf(e + 1.0f);
}

__global__ __launch_bounds__(256) void bio_kernel(
    const float* __restrict__ v,
    const float* __restrict__ na,
    const float* __restrict__ kk,
    const float* __restrict__ ca,
    float* __restrict__ out)
{
    int tid = blockIdx.x * 256 + (int)threadIdx.x;   // 4M threads
    int r  = tid >> 10;        // row, 0..4095  (1024 float4-quarters/row)
    int c4 = tid & 1023;
    int c  = c4 * 4;
    int base = r * WW + c;

    // reflect padding (mirror excluding edge)
    int rup = (r == 0)      ? 1      : r - 1;
    int rdn = (r == HH - 1) ? HH - 2 : r + 1;

    // voltage: cached loads (stencil halo is the only reused data)
    v4f vc = *(const v4f*)(v + base);
    v4f vu = *(const v4f*)(v + rup * WW + c);
    v4f vd = *(const v4f*)(v + rdn * WW + c);

    // single-use streams: non-temporal loads, keep L2/L3 for voltage
    v4f na4 = __builtin_nontemporal_load((const v4f*)(na + base));
    v4f k4  = __builtin_nontemporal_load((const v4f*)(kk + base));
    v4f ca4 = __builtin_nontemporal_load((const v4f*)(ca + base));

    // left/right neighbors via cross-lane shuffle instead of extra loads:
    // a wave's 64 lanes cover 256 contiguous floats of ONE row.
    float vl = __shfl_up(vc.w, 1);    // lane i <- lane i-1's last element
    float vr = __shfl_down(vc.x, 1);  // lane i <- lane i+1's first element
    int lane = (int)threadIdx.x & 63;
    if (lane == 0)  vl = (c == 0)      ? vc.y : v[base - 1];   // reflect: col 1
    if (lane == 63) vr = (c + 4 == WW) ? vc.z : v[base + 4];   // reflect: col W-2

    float cv[4]  = {vc.x, vc.y, vc.z, vc.w};
    float uu[4]  = {vu.x, vu.y, vu.z, vu.w};
    float dd[4]  = {vd.x, vd.y, vd.z, vd.w};
    float lf[4]  = {vl,   vc.x, vc.y, vc.z};
    float rt[4]  = {vc.y, vc.z, vc.w, vr};
    float nai[4] = {na4.x, na4.y, na4.z, na4.w};
    float ki[4]  = {k4.x,  k4.y,  k4.z,  k4.w};
    float cai[4] = {ca4.x, ca4.y, ca4.z, ca4.w};

    float o0[4], o1[4], o2[4], o3[4];
#pragma unroll
    for (int i = 0; i < 4; ++i) {
        float lap  = uu[i] + dd[i] + lf[i] + rt[i] - 4.0f * cv[i];
        float vupd = 0.5f * lap + 0.1f * nai[i] - 0.05f * ki[i] + 0.08f * cai[i];
        float nv   = fast_tanh(cv[i] + 0.1f * vupd);
        o0[i] = nv;
        o1[i] = nai[i] * 0.95f + 0.05f * fmaxf(nv, 0.0f);
        o2[i] = ki[i]  * 0.95f + 0.05f * fmaxf(-nv, 0.0f);
        o3[i] = cai[i] * 0.95f + 0.05f * fabsf(nv);
    }
    v4f ov  = (v4f){o0[0], o0[1], o0[2], o0[3]};
    v4f ona = (v4f){o1[0], o1[1], o1[2], o1[3]};
    v4f okk = (v4f){o2[0], o2[1], o2[2], o2[3]};
    v4f oca = (v4f){o3[0], o3[1], o3[2], o3[3]};

    const int HW = HH * WW;
    // streaming outputs: non-temporal, don't pollute L2/L3
    __builtin_nontemporal_store(ov,  (v4f*)(out + base));
    __builtin_nontemporal_store(ona, (v4f*)(out + HW + base));
    __builtin_nontemporal_store(okk, (v4f*)(out + 2 * HW + base));
    __builtin_nontemporal_store(oca, (v4f*)(out + 3 * HW + base));
}

extern "C" void kernel_launch(void* const* d_in, const int* in_sizes, int n_in,
                              void* d_out, int out_size, void* d_ws, size_t ws_size,
                              hipStream_t stream) {
    const float* v  = (const float*)d_in[0];
    const float* na = (const float*)d_in[1];
    const float* kk = (const float*)d_in[2];
    const float* ca = (const float*)d_in[3];
    float* out = (float*)d_out;

    int total = HH * (WW / 4);           // 4M threads, 4 cols each
    int block = 256;
    int grid  = (total + block - 1) / block;   // 16384
    bio_kernel<<<grid, block, 0, stream>>>(v, na, kk, ca, out);
}